// Round 6
// baseline (403.122 us; speedup 1.0000x reference)
//
#include <hip/hip_runtime.h>
#include <hip/hip_bf16.h>

#define N_NODES 50000
#define N_EDGES 800000
#define N_GRAPHS 64
#define IN_DIM 128
#define HID_DIM 256

typedef short sh8 __attribute__((ext_vector_type(8)));
typedef float f4 __attribute__((ext_vector_type(4)));
typedef unsigned short us4 __attribute__((ext_vector_type(4)));
typedef unsigned short us8 __attribute__((ext_vector_type(8)));

__device__ __forceinline__ unsigned short bf16rne(float f) {
    unsigned int u = __float_as_uint(f);
    return (unsigned short)((u + 0x7FFFu + ((u >> 16) & 1u)) >> 16);
}
__device__ __forceinline__ float bf2f(unsigned short b) {
    return __uint_as_float((unsigned int)b << 16);
}

// ---------------- degree / CSR build ----------------

__global__ void k_deg_count(const int* __restrict__ dst, int* __restrict__ deg) {
    int e = blockIdx.x * blockDim.x + threadIdx.x;
    if (e < N_EDGES) atomicAdd(&deg[dst[e]], 1);
}

#define SCAN_THREADS 1024
#define SCAN_CHUNK ((N_NODES + SCAN_THREADS - 1) / SCAN_THREADS)  // 49

// scan over degrees -> row_start; also emits dinv = rsqrt(deg+1)
__global__ __launch_bounds__(SCAN_THREADS)
void k_scan(const int* __restrict__ deg, int* __restrict__ row_start,
            float* __restrict__ dinv) {
    __shared__ int part[SCAN_THREADS];
    int t = threadIdx.x;
    int s0 = t * SCAN_CHUNK;
    int s1 = min(s0 + SCAN_CHUNK, N_NODES);
    int sum = 0;
    for (int i = s0; i < s1; ++i) {
        int d = deg[i];
        sum += d;
        dinv[i] = rsqrtf((float)d + 1.0f);
    }
    part[t] = sum;
    __syncthreads();
    for (int off = 1; off < SCAN_THREADS; off <<= 1) {
        int v = (t >= off) ? part[t - off] : 0;
        __syncthreads();
        part[t] += v;
        __syncthreads();
    }
    int run = part[t] - sum;
    for (int i = s0; i < s1; ++i) { row_start[i] = run; run += deg[i]; }
    if (t == SCAN_THREADS - 1) row_start[N_NODES] = run;
}

__global__ void k_csr_fill(const int* __restrict__ src, const int* __restrict__ dst,
                           const int* __restrict__ row_start, int* __restrict__ cursor,
                           int* __restrict__ col) {
    int e = blockIdx.x * blockDim.x + threadIdx.x;
    if (e < N_EDGES) {
        int d = dst[e];
        int pos = atomicAdd(&cursor[d], 1);
        col[row_start[d] + pos] = src[e];
    }
}

// ---------------- bf16 hi/lo split helpers ----------------

__device__ __forceinline__ void split_bf16(float f, unsigned short& h, unsigned short& l) {
    unsigned int u = __float_as_uint(f);
    unsigned int hb = (u + 0x7FFFu + ((u >> 16) & 1u)) & 0xFFFF0000u;  // RNE
    h = (unsigned short)(hb >> 16);
    float rest = f - __uint_as_float(hb);
    unsigned int u2 = __float_as_uint(rest);
    l = (unsigned short)((u2 + 0x7FFFu + ((u2 >> 16) & 1u)) >> 16);
}

__global__ void k_x2bf(const float* __restrict__ x, unsigned short* __restrict__ xb) {
    int i = blockIdx.x * blockDim.x + threadIdx.x;
    if (i >= N_NODES * IN_DIM / 4) return;
    float4 v = ((const float4*)x)[i];
    us4 o;
    o.x = bf16rne(v.x); o.y = bf16rne(v.y); o.z = bf16rne(v.z); o.w = bf16rne(v.w);
    ((us4*)xb)[i] = o;
}

// Pre-split W[K x 256] into hi/lo global images in fragment-major layout
__global__ void k_wsplit(const float* __restrict__ W, unsigned short* __restrict__ Bh,
                         unsigned short* __restrict__ Bl, int K) {
    int i = blockIdx.x * blockDim.x + threadIdx.x;
    if (i >= K * 256) return;
    int k = i >> 8, c = i & 255;
    unsigned short h, l;
    split_bf16(W[i], h, l);
    size_t pos = (size_t)(k >> 5) * 8192 + (size_t)(((c >> 4) * 4 + ((k >> 3) & 3)) * 128 + (c & 15) * 8 + (k & 7));
    Bh[pos] = h;
    Bl[pos] = l;
}

// ---------------- MFMA GEMM: [M,256] = epilogue(A[M,K] @ B[K,256]) --------
// 64x256 tile per block, 4 waves (each 64x64), K-step 32, 3-pass hi/lo split.
// MODE 0: Yb[m,c] = bf16(acc * dinv[m]);  MODE 1: C[m,c] = relu(acc + bias[c])

template<int MODE>
__global__ __launch_bounds__(256)
void k_gemm_mfma(const float* __restrict__ A, const unsigned short* __restrict__ Bh,
                 const unsigned short* __restrict__ Bl, const float* __restrict__ dinv,
                 const float* __restrict__ bias, float* __restrict__ C,
                 unsigned short* __restrict__ Yb, int M, int K) {
    __shared__ unsigned short AhL[2048], AlL[2048];
    __shared__ unsigned short BhL[8192], BlL[8192];

    const int tid = threadIdx.x;
    const int wv = tid >> 6, lane = tid & 63;
    const int m0 = blockIdx.x * 64;

    const int arow = tid >> 2, aseg = tid & 3;
    const int agrow = m0 + arow;
    const bool aval = (agrow < M);
    const float* aptr = A + (size_t)agrow * K + aseg * 8;
    const int aslot = ((arow >> 4) * 4 + aseg) * 16 + (arow & 15);

    f4 acc[4][4];
    #pragma unroll
    for (int mi = 0; mi < 4; ++mi)
        #pragma unroll
        for (int nj = 0; nj < 4; ++nj)
            acc[mi][nj] = f4{0.f, 0.f, 0.f, 0.f};

    const int nsteps = K >> 5;
    for (int s = 0; s < nsteps; ++s) {
        float4 va = make_float4(0.f, 0.f, 0.f, 0.f);
        float4 vb = make_float4(0.f, 0.f, 0.f, 0.f);
        if (aval) {
            va = *reinterpret_cast<const float4*>(aptr + s * 32);
            vb = *reinterpret_cast<const float4*>(aptr + s * 32 + 4);
        }
        sh8 bh[4], bl[4];
        {
            const unsigned short* gb = Bh + (size_t)s * 8192;
            const unsigned short* gl = Bl + (size_t)s * 8192;
            #pragma unroll
            for (int j = 0; j < 4; ++j) {
                bh[j] = *reinterpret_cast<const sh8*>(gb + j * 2048 + tid * 8);
                bl[j] = *reinterpret_cast<const sh8*>(gl + j * 2048 + tid * 8);
            }
        }
        __syncthreads();

        {
            float f[8] = {va.x, va.y, va.z, va.w, vb.x, vb.y, vb.z, vb.w};
            sh8 hv, lv;
            #pragma unroll
            for (int e = 0; e < 8; ++e) {
                unsigned short h, l;
                split_bf16(f[e], h, l);
                hv[e] = (short)h;
                lv[e] = (short)l;
            }
            *reinterpret_cast<sh8*>(&AhL[aslot * 8]) = hv;
            *reinterpret_cast<sh8*>(&AlL[aslot * 8]) = lv;
        }
        #pragma unroll
        for (int j = 0; j < 4; ++j) {
            *reinterpret_cast<sh8*>(&BhL[j * 2048 + tid * 8]) = bh[j];
            *reinterpret_cast<sh8*>(&BlL[j * 2048 + tid * 8]) = bl[j];
        }
        __syncthreads();

        sh8 afh[4], afl[4], bfh[4], bfl[4];
        #pragma unroll
        for (int mi = 0; mi < 4; ++mi) {
            afh[mi] = *reinterpret_cast<const sh8*>(&AhL[mi * 512 + lane * 8]);
            afl[mi] = *reinterpret_cast<const sh8*>(&AlL[mi * 512 + lane * 8]);
        }
        #pragma unroll
        for (int nj = 0; nj < 4; ++nj) {
            bfh[nj] = *reinterpret_cast<const sh8*>(&BhL[(wv * 4 + nj) * 512 + lane * 8]);
            bfl[nj] = *reinterpret_cast<const sh8*>(&BlL[(wv * 4 + nj) * 512 + lane * 8]);
        }
        #pragma unroll
        for (int mi = 0; mi < 4; ++mi) {
            #pragma unroll
            for (int nj = 0; nj < 4; ++nj) {
                acc[mi][nj] = __builtin_amdgcn_mfma_f32_16x16x32_bf16(afh[mi], bfh[nj], acc[mi][nj], 0, 0, 0);
                acc[mi][nj] = __builtin_amdgcn_mfma_f32_16x16x32_bf16(afh[mi], bfl[nj], acc[mi][nj], 0, 0, 0);
                acc[mi][nj] = __builtin_amdgcn_mfma_f32_16x16x32_bf16(afl[mi], bfh[nj], acc[mi][nj], 0, 0, 0);
            }
        }
    }

    #pragma unroll
    for (int mi = 0; mi < 4; ++mi) {
        #pragma unroll
        for (int q = 0; q < 4; ++q) {
            int grow = m0 + mi * 16 + (lane >> 4) * 4 + q;
            if (grow < M) {
                float dm = (MODE == 0) ? dinv[grow] : 0.f;
                #pragma unroll
                for (int nj = 0; nj < 4; ++nj) {
                    int gcol = wv * 64 + nj * 16 + (lane & 15);
                    float v = acc[mi][nj][q];
                    if (MODE == 0) {
                        Yb[(size_t)grow * 256 + gcol] = bf16rne(v * dm);
                    } else {
                        C[(size_t)grow * 256 + gcol] = fmaxf(v + bias[gcol], 0.f);
                    }
                }
            }
        }
    }
}

// ---------------- aggregation ----------------

// layer-1: z[n] = dinv[n] * ( dinv[n]*x[n] + sum dinv[s]*xb[s] )
// Half-wave dual-edge + 4x unroll: 8 independent gathers in flight per wave.
__global__ __launch_bounds__(256)
void k_agg_x(const float* __restrict__ x, const unsigned short* __restrict__ xb,
             const int* __restrict__ row_start, const int* __restrict__ col,
             const float* __restrict__ dinv, float* __restrict__ z) {
    int wv = threadIdx.x >> 6, lane = threadIdx.x & 63;
    int half = lane >> 5, sub = lane & 31;
    int n = blockIdx.x * 4 + wv;
    bool valid = (n < N_NODES);

    float a0 = 0.f, a1 = 0.f, a2 = 0.f, a3 = 0.f;
    float dn = 0.f;
    if (valid) {
        dn = dinv[n];
        if (half == 0) {
            float4 xs = ((const float4*)x)[(size_t)n * 32 + sub];
            a0 = xs.x * dn; a1 = xs.y * dn; a2 = xs.z * dn; a3 = xs.w * dn;
        }
        const us4* xb4 = (const us4*)xb;
        int e = row_start[n] + half;
        const int e1 = row_start[n + 1];
        for (; e + 6 < e1; e += 8) {
            int s0 = col[e], s1 = col[e + 2], s2 = col[e + 4], s3 = col[e + 6];
            float d0 = dinv[s0], d1 = dinv[s1], d2 = dinv[s2], d3 = dinv[s3];
            us4 v0 = xb4[(size_t)s0 * 32 + sub];
            us4 v1 = xb4[(size_t)s1 * 32 + sub];
            us4 v2 = xb4[(size_t)s2 * 32 + sub];
            us4 v3 = xb4[(size_t)s3 * 32 + sub];
            a0 += bf2f(v0.x) * d0 + bf2f(v1.x) * d1 + bf2f(v2.x) * d2 + bf2f(v3.x) * d3;
            a1 += bf2f(v0.y) * d0 + bf2f(v1.y) * d1 + bf2f(v2.y) * d2 + bf2f(v3.y) * d3;
            a2 += bf2f(v0.z) * d0 + bf2f(v1.z) * d1 + bf2f(v2.z) * d2 + bf2f(v3.z) * d3;
            a3 += bf2f(v0.w) * d0 + bf2f(v1.w) * d1 + bf2f(v2.w) * d2 + bf2f(v3.w) * d3;
        }
        for (; e < e1; e += 2) {
            int s = col[e];
            float ds = dinv[s];
            us4 v = xb4[(size_t)s * 32 + sub];
            a0 += bf2f(v.x) * ds; a1 += bf2f(v.y) * ds;
            a2 += bf2f(v.z) * ds; a3 += bf2f(v.w) * ds;
        }
    }
    a0 += __shfl_xor(a0, 32, 64);
    a1 += __shfl_xor(a1, 32, 64);
    a2 += __shfl_xor(a2, 32, 64);
    a3 += __shfl_xor(a3, 32, 64);
    if (valid && half == 0) {
        float4 o;
        o.x = a0 * dn; o.y = a1 * dn; o.z = a2 * dn; o.w = a3 * dn;
        ((float4*)z)[(size_t)n * 32 + sub] = o;
    }
}

// layer-2 agg + relu + mean-pool fused. yb pre-scaled by dinv[src] (bf16).
// 8 nodes per 512-thread block (N_NODES % 8 == 0: every n valid).
// Half-wave dual-edge + 4x unroll. Per-wave private LDS slice (no LDS atomics).
__global__ __launch_bounds__(512)
void k_agg_pool(const unsigned short* __restrict__ yb, const int* __restrict__ row_start,
                const int* __restrict__ col, const float* __restrict__ dinv,
                const float* __restrict__ bias, const int* __restrict__ batch,
                float* __restrict__ sums) {
    __shared__ float lsum[8][256];
    const int tid = threadIdx.x;
    const int wv = tid >> 6, lane = tid & 63;
    const int half = lane >> 5, sub = lane & 31;
    const int base = blockIdx.x * 8;
    const int n = base + wv;

    const bool uni = (batch[base] == batch[base + 7]);

    const us8* y8 = (const us8*)yb;
    float a[8] = {0.f, 0.f, 0.f, 0.f, 0.f, 0.f, 0.f, 0.f};
    if (half == 0) {
        us8 sv = y8[(size_t)n * 32 + sub];
        #pragma unroll
        for (int j = 0; j < 8; ++j) a[j] = bf2f(sv[j]);
    }
    int e = row_start[n] + half;
    const int e1 = row_start[n + 1];
    for (; e + 6 < e1; e += 8) {
        int s0 = col[e], s1 = col[e + 2], s2 = col[e + 4], s3 = col[e + 6];
        us8 v0 = y8[(size_t)s0 * 32 + sub];
        us8 v1 = y8[(size_t)s1 * 32 + sub];
        us8 v2 = y8[(size_t)s2 * 32 + sub];
        us8 v3 = y8[(size_t)s3 * 32 + sub];
        #pragma unroll
        for (int j = 0; j < 8; ++j)
            a[j] += (bf2f(v0[j]) + bf2f(v1[j])) + (bf2f(v2[j]) + bf2f(v3[j]));
    }
    for (; e < e1; e += 2) {
        int s = col[e];
        us8 v = y8[(size_t)s * 32 + sub];
        #pragma unroll
        for (int j = 0; j < 8; ++j) a[j] += bf2f(v[j]);
    }
    #pragma unroll
    for (int j = 0; j < 8; ++j) a[j] += __shfl_xor(a[j], 32, 64);

    if (half == 0) {
        float dn = dinv[n];
        float4 b0 = ((const float4*)bias)[sub * 2];
        float4 b1 = ((const float4*)bias)[sub * 2 + 1];
        float4 o0, o1;
        o0.x = fmaxf(a[0] * dn + b0.x, 0.f);
        o0.y = fmaxf(a[1] * dn + b0.y, 0.f);
        o0.z = fmaxf(a[2] * dn + b0.z, 0.f);
        o0.w = fmaxf(a[3] * dn + b0.w, 0.f);
        o1.x = fmaxf(a[4] * dn + b1.x, 0.f);
        o1.y = fmaxf(a[5] * dn + b1.y, 0.f);
        o1.z = fmaxf(a[6] * dn + b1.z, 0.f);
        o1.w = fmaxf(a[7] * dn + b1.w, 0.f);
        if (uni) {
            ((float4*)&lsum[wv][sub * 8])[0] = o0;
            ((float4*)&lsum[wv][sub * 8])[1] = o1;
        } else {
            int g = batch[n];
            atomicAdd(&sums[g * 256 + sub * 8 + 0], o0.x);
            atomicAdd(&sums[g * 256 + sub * 8 + 1], o0.y);
            atomicAdd(&sums[g * 256 + sub * 8 + 2], o0.z);
            atomicAdd(&sums[g * 256 + sub * 8 + 3], o0.w);
            atomicAdd(&sums[g * 256 + sub * 8 + 4], o1.x);
            atomicAdd(&sums[g * 256 + sub * 8 + 5], o1.y);
            atomicAdd(&sums[g * 256 + sub * 8 + 6], o1.z);
            atomicAdd(&sums[g * 256 + sub * 8 + 7], o1.w);
        }
    }
    __syncthreads();
    if (uni && tid < 256) {
        float v = 0.f;
        #pragma unroll
        for (int w = 0; w < 8; ++w) v += lsum[w][tid];
        atomicAdd(&sums[batch[base] * 256 + tid], v);
    }
}

// ---------------- bounds + sums-init (merged) + FC ----------------

__global__ __launch_bounds__(512)
void k_bounds_init(const int* __restrict__ batch, int* __restrict__ bounds,
                   float* __restrict__ sums) {
    int t = threadIdx.x;
    if (t <= N_GRAPHS) {
        int lo = 0, hi = N_NODES;
        while (lo < hi) {
            int mid = (lo + hi) >> 1;
            if (batch[mid] < t) lo = mid + 1; else hi = mid;
        }
        bounds[t] = lo;
    }
    for (int i = t; i < N_GRAPHS * HID_DIM; i += 512) sums[i] = 0.f;
}

__global__ void k_final(const float* __restrict__ sums, const int* __restrict__ bounds,
                        const float* __restrict__ Wfc, const float* __restrict__ bfc,
                        float* __restrict__ out) {
    __shared__ float red[HID_DIM];
    int g = blockIdx.x;
    int c = threadIdx.x;
    float cnt = (float)(bounds[g + 1] - bounds[g]);
    float v = sums[g * HID_DIM + c] / fmaxf(cnt, 1.0f) * Wfc[c];
    red[c] = v;
    __syncthreads();
    for (int s = HID_DIM / 2; s > 0; s >>= 1) {
        if (c < s) red[c] += red[c + s];
        __syncthreads();
    }
    if (c == 0) out[g] = red[0] + bfc[0];
}

// ---------------- launch ----------------

extern "C" void kernel_launch(void* const* d_in, const int* in_sizes, int n_in,
                              void* d_out, int out_size, void* d_ws, size_t ws_size,
                              hipStream_t stream) {
    const float* x    = (const float*)d_in[0];
    const int*   ei   = (const int*)d_in[1];
    const int*   batch= (const int*)d_in[2];
    const float* W1   = (const float*)d_in[3];
    const float* b1   = (const float*)d_in[4];
    const float* W2   = (const float*)d_in[5];
    const float* b2   = (const float*)d_in[6];
    const float* Wfc  = (const float*)d_in[7];
    const float* bfc  = (const float*)d_in[8];
    float* out = (float*)d_out;

    const int* src = ei;
    const int* dst = ei + N_EDGES;

    char* ws = (char*)d_ws;
    const size_t BUF_BYTES = (size_t)N_NODES * HID_DIM * sizeof(float);  // 51.2 MB
    size_t off = 0;
    float* region0   = (float*)(ws + off); off += BUF_BYTES;   // h1
    char*  region1   = (char*) (ws + off); off += BUF_BYTES;   // z/y2b front, xb back
    int*   deg_i     = (int*)  (ws + off); off += 200704;
    int*   cursor    = (int*)  (ws + off); off += 200704;
    float* dinv      = (float*)(ws + off); off += 200704;
    int*   row_start = (int*)  (ws + off); off += 200704;
    int*   col       = (int*)  (ws + off); off += (size_t)N_EDGES * 4;
    unsigned short* Bh1 = (unsigned short*)(ws + off); off += 65536;
    unsigned short* Bl1 = (unsigned short*)(ws + off); off += 65536;
    unsigned short* Bh2 = (unsigned short*)(ws + off); off += 131072;
    unsigned short* Bl2 = (unsigned short*)(ws + off); off += 131072;
    float* sums      = (float*)(ws + off); off += 65536;
    int*   bounds    = (int*)  (ws + off); off += 512;
    (void)ws_size; (void)in_sizes; (void)n_in; (void)out_size;

    // region1 overlays (lifetimes disjoint):
    //   z   [N,128] fp32 : front — written by agg_x, read by GEMM1, then dead
    //   y2b [N,256] bf16 : front — written by GEMM2, read by agg_pool
    //   xb  [N,128] bf16 : back  — written by x2bf, read by agg_x, then dead
    float*          z   = (float*)region1;
    unsigned short* y2b = (unsigned short*)region1;
    unsigned short* xb  = (unsigned short*)(region1 + (size_t)N_NODES * IN_DIM * sizeof(float));
    float* h1 = region0;

    // 1. CSR build + dinv + weight split + x->bf16
    hipMemsetAsync(deg_i, 0, 2 * 200704, stream);
    k_deg_count<<<(N_EDGES + 255) / 256, 256, 0, stream>>>(dst, deg_i);
    k_scan<<<1, SCAN_THREADS, 0, stream>>>(deg_i, row_start, dinv);
    k_csr_fill<<<(N_EDGES + 255) / 256, 256, 0, stream>>>(src, dst, row_start, cursor, col);
    k_x2bf<<<(N_NODES * IN_DIM / 4 + 255) / 256, 256, 0, stream>>>(x, xb);
    k_wsplit<<<(IN_DIM * 256 + 255) / 256, 256, 0, stream>>>(W1, Bh1, Bl1, IN_DIM);
    k_wsplit<<<(HID_DIM * 256 + 255) / 256, 256, 0, stream>>>(W2, Bh2, Bl2, HID_DIM);
    k_bounds_init<<<1, 512, 0, stream>>>(batch, bounds, sums);

    const int gemm_grid = (N_NODES + 63) / 64;  // 782

    // 2. layer 1: z = A_hat @ x ; h1 = relu(z @ W1 + b1)
    k_agg_x<<<(N_NODES + 3) / 4, 256, 0, stream>>>(x, xb, row_start, col, dinv, z);
    k_gemm_mfma<1><<<gemm_grid, 256, 0, stream>>>(z, Bh1, Bl1, dinv, b1, h1, nullptr, N_NODES, IN_DIM);

    // 3. layer 2: y2b = bf16((h1 @ W2) * dinv) ; fused agg+relu+pool
    k_gemm_mfma<0><<<gemm_grid, 256, 0, stream>>>(h1, Bh2, Bl2, dinv, b2, nullptr, y2b, N_NODES, HID_DIM);
    k_agg_pool<<<(N_NODES + 7) / 8, 512, 0, stream>>>(y2b, row_start, col, dinv, b2, batch, sums);

    // 4. fc
    k_final<<<N_GRAPHS, HID_DIM, 0, stream>>>(sums, bounds, Wfc, bfc, out);
}

// Round 7
// 279.202 us; speedup vs baseline: 1.4438x; 1.4438x over previous
//
#include <hip/hip_runtime.h>
#include <hip/hip_bf16.h>

#define N_NODES 50000
#define N_EDGES 800000
#define N_GRAPHS 64
#define IN_DIM 128
#define HID_DIM 256

typedef short sh8 __attribute__((ext_vector_type(8)));
typedef float f4 __attribute__((ext_vector_type(4)));
typedef unsigned short us4 __attribute__((ext_vector_type(4)));
typedef unsigned short us8 __attribute__((ext_vector_type(8)));

__device__ __forceinline__ unsigned short bf16rne(float f) {
    unsigned int u = __float_as_uint(f);
    return (unsigned short)((u + 0x7FFFu + ((u >> 16) & 1u)) >> 16);
}
__device__ __forceinline__ float bf2f(unsigned short b) {
    return __uint_as_float((unsigned int)b << 16);
}

// ---------------- degree / CSR build ----------------

__global__ void k_deg_count(const int* __restrict__ dst, int* __restrict__ deg) {
    int e = blockIdx.x * blockDim.x + threadIdx.x;
    if (e < N_EDGES) atomicAdd(&deg[dst[e]], 1);
}

#define SCAN_BLK 1024
#define SCAN_NBLK ((N_NODES + SCAN_BLK - 1) / SCAN_BLK)  // 49

// Phase 1: per-block scan. row_start[i] = exclusive prefix within block,
// blk_tot[b] = block sum. Also emits dinv = rsqrt(deg+1).
__global__ __launch_bounds__(SCAN_BLK)
void k_scan_blk(const int* __restrict__ deg, int* __restrict__ row_start,
                float* __restrict__ dinv, int* __restrict__ blk_tot) {
    __shared__ int tmp[SCAN_BLK];
    int t = threadIdx.x;
    int i = blockIdx.x * SCAN_BLK + t;
    int d = 0;
    if (i < N_NODES) {
        d = deg[i];
        dinv[i] = rsqrtf((float)d + 1.0f);
    }
    tmp[t] = d;
    __syncthreads();
    #pragma unroll
    for (int off = 1; off < SCAN_BLK; off <<= 1) {
        int v = (t >= off) ? tmp[t - off] : 0;
        __syncthreads();
        tmp[t] += v;
        __syncthreads();
    }
    if (i < N_NODES) row_start[i] = tmp[t] - d;   // exclusive (block-local)
    if (t == SCAN_BLK - 1) blk_tot[blockIdx.x] = tmp[t];
}

// Phase 2: add block offsets. Wave 0 computes sum(blk_tot[0..bid)).
__global__ __launch_bounds__(SCAN_BLK)
void k_scan_add(int* __restrict__ row_start, const int* __restrict__ blk_tot) {
    __shared__ int soff;
    int t = threadIdx.x;
    int bid = blockIdx.x;
    if (t < 64) {
        int v = (t < bid) ? blk_tot[t] : 0;   // bid <= 48 < 64
        #pragma unroll
        for (int m = 1; m < 64; m <<= 1) v += __shfl_xor(v, m, 64);
        if (t == 0) soff = v;
    }
    __syncthreads();
    int i = bid * SCAN_BLK + t;
    if (i < N_NODES) row_start[i] += soff;
    if (bid == 0 && t == 0) row_start[N_NODES] = N_EDGES;
}

__global__ void k_csr_fill(const int* __restrict__ src, const int* __restrict__ dst,
                           const int* __restrict__ row_start, int* __restrict__ cursor,
                           int* __restrict__ col) {
    int e = blockIdx.x * blockDim.x + threadIdx.x;
    if (e < N_EDGES) {
        int d = dst[e];
        int pos = atomicAdd(&cursor[d], 1);
        col[row_start[d] + pos] = src[e];
    }
}

// ---------------- bf16 hi/lo split helpers ----------------

__device__ __forceinline__ void split_bf16(float f, unsigned short& h, unsigned short& l) {
    unsigned int u = __float_as_uint(f);
    unsigned int hb = (u + 0x7FFFu + ((u >> 16) & 1u)) & 0xFFFF0000u;  // RNE
    h = (unsigned short)(hb >> 16);
    float rest = f - __uint_as_float(hb);
    unsigned int u2 = __float_as_uint(rest);
    l = (unsigned short)((u2 + 0x7FFFu + ((u2 >> 16) & 1u)) >> 16);
}

__global__ void k_x2bf(const float* __restrict__ x, unsigned short* __restrict__ xb) {
    int i = blockIdx.x * blockDim.x + threadIdx.x;
    if (i >= N_NODES * IN_DIM / 4) return;
    float4 v = ((const float4*)x)[i];
    us4 o;
    o.x = bf16rne(v.x); o.y = bf16rne(v.y); o.z = bf16rne(v.z); o.w = bf16rne(v.w);
    ((us4*)xb)[i] = o;
}

// Pre-split W[K x 256] into hi/lo global images in fragment-major layout
__global__ void k_wsplit(const float* __restrict__ W, unsigned short* __restrict__ Bh,
                         unsigned short* __restrict__ Bl, int K) {
    int i = blockIdx.x * blockDim.x + threadIdx.x;
    if (i >= K * 256) return;
    int k = i >> 8, c = i & 255;
    unsigned short h, l;
    split_bf16(W[i], h, l);
    size_t pos = (size_t)(k >> 5) * 8192 + (size_t)(((c >> 4) * 4 + ((k >> 3) & 3)) * 128 + (c & 15) * 8 + (k & 7));
    Bh[pos] = h;
    Bl[pos] = l;
}

// ---------------- MFMA GEMM: [M,256] = epilogue(A[M,K] @ B[K,256]) --------
// 64x256 tile per block, 4 waves (each 64x64), K-step 32, 3-pass hi/lo split.
// MODE 0: Yb[m,c] = bf16(acc * dinv[m]);  MODE 1: C[m,c] = relu(acc + bias[c])

template<int MODE>
__global__ __launch_bounds__(256)
void k_gemm_mfma(const float* __restrict__ A, const unsigned short* __restrict__ Bh,
                 const unsigned short* __restrict__ Bl, const float* __restrict__ dinv,
                 const float* __restrict__ bias, float* __restrict__ C,
                 unsigned short* __restrict__ Yb, int M, int K) {
    __shared__ unsigned short AhL[2048], AlL[2048];
    __shared__ unsigned short BhL[8192], BlL[8192];

    const int tid = threadIdx.x;
    const int wv = tid >> 6, lane = tid & 63;
    const int m0 = blockIdx.x * 64;

    const int arow = tid >> 2, aseg = tid & 3;
    const int agrow = m0 + arow;
    const bool aval = (agrow < M);
    const float* aptr = A + (size_t)agrow * K + aseg * 8;
    const int aslot = ((arow >> 4) * 4 + aseg) * 16 + (arow & 15);

    f4 acc[4][4];
    #pragma unroll
    for (int mi = 0; mi < 4; ++mi)
        #pragma unroll
        for (int nj = 0; nj < 4; ++nj)
            acc[mi][nj] = f4{0.f, 0.f, 0.f, 0.f};

    const int nsteps = K >> 5;
    for (int s = 0; s < nsteps; ++s) {
        float4 va = make_float4(0.f, 0.f, 0.f, 0.f);
        float4 vb = make_float4(0.f, 0.f, 0.f, 0.f);
        if (aval) {
            va = *reinterpret_cast<const float4*>(aptr + s * 32);
            vb = *reinterpret_cast<const float4*>(aptr + s * 32 + 4);
        }
        sh8 bh[4], bl[4];
        {
            const unsigned short* gb = Bh + (size_t)s * 8192;
            const unsigned short* gl = Bl + (size_t)s * 8192;
            #pragma unroll
            for (int j = 0; j < 4; ++j) {
                bh[j] = *reinterpret_cast<const sh8*>(gb + j * 2048 + tid * 8);
                bl[j] = *reinterpret_cast<const sh8*>(gl + j * 2048 + tid * 8);
            }
        }
        __syncthreads();

        {
            float f[8] = {va.x, va.y, va.z, va.w, vb.x, vb.y, vb.z, vb.w};
            sh8 hv, lv;
            #pragma unroll
            for (int e = 0; e < 8; ++e) {
                unsigned short h, l;
                split_bf16(f[e], h, l);
                hv[e] = (short)h;
                lv[e] = (short)l;
            }
            *reinterpret_cast<sh8*>(&AhL[aslot * 8]) = hv;
            *reinterpret_cast<sh8*>(&AlL[aslot * 8]) = lv;
        }
        #pragma unroll
        for (int j = 0; j < 4; ++j) {
            *reinterpret_cast<sh8*>(&BhL[j * 2048 + tid * 8]) = bh[j];
            *reinterpret_cast<sh8*>(&BlL[j * 2048 + tid * 8]) = bl[j];
        }
        __syncthreads();

        sh8 afh[4], afl[4], bfh[4], bfl[4];
        #pragma unroll
        for (int mi = 0; mi < 4; ++mi) {
            afh[mi] = *reinterpret_cast<const sh8*>(&AhL[mi * 512 + lane * 8]);
            afl[mi] = *reinterpret_cast<const sh8*>(&AlL[mi * 512 + lane * 8]);
        }
        #pragma unroll
        for (int nj = 0; nj < 4; ++nj) {
            bfh[nj] = *reinterpret_cast<const sh8*>(&BhL[(wv * 4 + nj) * 512 + lane * 8]);
            bfl[nj] = *reinterpret_cast<const sh8*>(&BlL[(wv * 4 + nj) * 512 + lane * 8]);
        }
        #pragma unroll
        for (int mi = 0; mi < 4; ++mi) {
            #pragma unroll
            for (int nj = 0; nj < 4; ++nj) {
                acc[mi][nj] = __builtin_amdgcn_mfma_f32_16x16x32_bf16(afh[mi], bfh[nj], acc[mi][nj], 0, 0, 0);
                acc[mi][nj] = __builtin_amdgcn_mfma_f32_16x16x32_bf16(afh[mi], bfl[nj], acc[mi][nj], 0, 0, 0);
                acc[mi][nj] = __builtin_amdgcn_mfma_f32_16x16x32_bf16(afl[mi], bfh[nj], acc[mi][nj], 0, 0, 0);
            }
        }
    }

    #pragma unroll
    for (int mi = 0; mi < 4; ++mi) {
        #pragma unroll
        for (int q = 0; q < 4; ++q) {
            int grow = m0 + mi * 16 + (lane >> 4) * 4 + q;
            if (grow < M) {
                float dm = (MODE == 0) ? dinv[grow] : 0.f;
                #pragma unroll
                for (int nj = 0; nj < 4; ++nj) {
                    int gcol = wv * 64 + nj * 16 + (lane & 15);
                    float v = acc[mi][nj][q];
                    if (MODE == 0) {
                        Yb[(size_t)grow * 256 + gcol] = bf16rne(v * dm);
                    } else {
                        C[(size_t)grow * 256 + gcol] = fmaxf(v + bias[gcol], 0.f);
                    }
                }
            }
        }
    }
}

// ---------------- aggregation ----------------

// layer-1: z[n] = dinv[n] * ( dinv[n]*x[n] + sum dinv[s]*xb[s] )
// Half-wave dual-edge + 4x unroll: 8 independent gathers in flight per wave.
__global__ __launch_bounds__(256)
void k_agg_x(const float* __restrict__ x, const unsigned short* __restrict__ xb,
             const int* __restrict__ row_start, const int* __restrict__ col,
             const float* __restrict__ dinv, float* __restrict__ z) {
    int wv = threadIdx.x >> 6, lane = threadIdx.x & 63;
    int half = lane >> 5, sub = lane & 31;
    int n = blockIdx.x * 4 + wv;
    bool valid = (n < N_NODES);

    float a0 = 0.f, a1 = 0.f, a2 = 0.f, a3 = 0.f;
    float dn = 0.f;
    if (valid) {
        dn = dinv[n];
        if (half == 0) {
            float4 xs = ((const float4*)x)[(size_t)n * 32 + sub];
            a0 = xs.x * dn; a1 = xs.y * dn; a2 = xs.z * dn; a3 = xs.w * dn;
        }
        const us4* xb4 = (const us4*)xb;
        int e = row_start[n] + half;
        const int e1 = row_start[n + 1];
        for (; e + 6 < e1; e += 8) {
            int s0 = col[e], s1 = col[e + 2], s2 = col[e + 4], s3 = col[e + 6];
            float d0 = dinv[s0], d1 = dinv[s1], d2 = dinv[s2], d3 = dinv[s3];
            us4 v0 = xb4[(size_t)s0 * 32 + sub];
            us4 v1 = xb4[(size_t)s1 * 32 + sub];
            us4 v2 = xb4[(size_t)s2 * 32 + sub];
            us4 v3 = xb4[(size_t)s3 * 32 + sub];
            a0 += bf2f(v0.x) * d0 + bf2f(v1.x) * d1 + bf2f(v2.x) * d2 + bf2f(v3.x) * d3;
            a1 += bf2f(v0.y) * d0 + bf2f(v1.y) * d1 + bf2f(v2.y) * d2 + bf2f(v3.y) * d3;
            a2 += bf2f(v0.z) * d0 + bf2f(v1.z) * d1 + bf2f(v2.z) * d2 + bf2f(v3.z) * d3;
            a3 += bf2f(v0.w) * d0 + bf2f(v1.w) * d1 + bf2f(v2.w) * d2 + bf2f(v3.w) * d3;
        }
        for (; e < e1; e += 2) {
            int s = col[e];
            float ds = dinv[s];
            us4 v = xb4[(size_t)s * 32 + sub];
            a0 += bf2f(v.x) * ds; a1 += bf2f(v.y) * ds;
            a2 += bf2f(v.z) * ds; a3 += bf2f(v.w) * ds;
        }
    }
    a0 += __shfl_xor(a0, 32, 64);
    a1 += __shfl_xor(a1, 32, 64);
    a2 += __shfl_xor(a2, 32, 64);
    a3 += __shfl_xor(a3, 32, 64);
    if (valid && half == 0) {
        float4 o;
        o.x = a0 * dn; o.y = a1 * dn; o.z = a2 * dn; o.w = a3 * dn;
        ((float4*)z)[(size_t)n * 32 + sub] = o;
    }
}

// layer-2 agg + relu + mean-pool fused. yb pre-scaled by dinv[src] (bf16).
// 8 nodes per 512-thread block. Half-wave dual-edge + 4x unroll.
// Per-wave private LDS slice (no LDS atomics).
__global__ __launch_bounds__(512)
void k_agg_pool(const unsigned short* __restrict__ yb, const int* __restrict__ row_start,
                const int* __restrict__ col, const float* __restrict__ dinv,
                const float* __restrict__ bias, const int* __restrict__ batch,
                float* __restrict__ sums) {
    __shared__ float lsum[8][256];
    const int tid = threadIdx.x;
    const int wv = tid >> 6, lane = tid & 63;
    const int half = lane >> 5, sub = lane & 31;
    const int base = blockIdx.x * 8;
    const int n = base + wv;

    const bool uni = (batch[base] == batch[base + 7]);

    const us8* y8 = (const us8*)yb;
    float a[8] = {0.f, 0.f, 0.f, 0.f, 0.f, 0.f, 0.f, 0.f};
    if (half == 0) {
        us8 sv = y8[(size_t)n * 32 + sub];
        #pragma unroll
        for (int j = 0; j < 8; ++j) a[j] = bf2f(sv[j]);
    }
    int e = row_start[n] + half;
    const int e1 = row_start[n + 1];
    for (; e + 6 < e1; e += 8) {
        int s0 = col[e], s1 = col[e + 2], s2 = col[e + 4], s3 = col[e + 6];
        us8 v0 = y8[(size_t)s0 * 32 + sub];
        us8 v1 = y8[(size_t)s1 * 32 + sub];
        us8 v2 = y8[(size_t)s2 * 32 + sub];
        us8 v3 = y8[(size_t)s3 * 32 + sub];
        #pragma unroll
        for (int j = 0; j < 8; ++j)
            a[j] += (bf2f(v0[j]) + bf2f(v1[j])) + (bf2f(v2[j]) + bf2f(v3[j]));
    }
    for (; e < e1; e += 2) {
        int s = col[e];
        us8 v = y8[(size_t)s * 32 + sub];
        #pragma unroll
        for (int j = 0; j < 8; ++j) a[j] += bf2f(v[j]);
    }
    #pragma unroll
    for (int j = 0; j < 8; ++j) a[j] += __shfl_xor(a[j], 32, 64);

    if (half == 0) {
        float dn = dinv[n];
        float4 b0 = ((const float4*)bias)[sub * 2];
        float4 b1 = ((const float4*)bias)[sub * 2 + 1];
        float4 o0, o1;
        o0.x = fmaxf(a[0] * dn + b0.x, 0.f);
        o0.y = fmaxf(a[1] * dn + b0.y, 0.f);
        o0.z = fmaxf(a[2] * dn + b0.z, 0.f);
        o0.w = fmaxf(a[3] * dn + b0.w, 0.f);
        o1.x = fmaxf(a[4] * dn + b1.x, 0.f);
        o1.y = fmaxf(a[5] * dn + b1.y, 0.f);
        o1.z = fmaxf(a[6] * dn + b1.z, 0.f);
        o1.w = fmaxf(a[7] * dn + b1.w, 0.f);
        if (uni) {
            ((float4*)&lsum[wv][sub * 8])[0] = o0;
            ((float4*)&lsum[wv][sub * 8])[1] = o1;
        } else {
            int g = batch[n];
            atomicAdd(&sums[g * 256 + sub * 8 + 0], o0.x);
            atomicAdd(&sums[g * 256 + sub * 8 + 1], o0.y);
            atomicAdd(&sums[g * 256 + sub * 8 + 2], o0.z);
            atomicAdd(&sums[g * 256 + sub * 8 + 3], o0.w);
            atomicAdd(&sums[g * 256 + sub * 8 + 4], o1.x);
            atomicAdd(&sums[g * 256 + sub * 8 + 5], o1.y);
            atomicAdd(&sums[g * 256 + sub * 8 + 6], o1.z);
            atomicAdd(&sums[g * 256 + sub * 8 + 7], o1.w);
        }
    }
    __syncthreads();
    if (uni && tid < 256) {
        float v = 0.f;
        #pragma unroll
        for (int w = 0; w < 8; ++w) v += lsum[w][tid];
        atomicAdd(&sums[batch[base] * 256 + tid], v);
    }
}

// ---------------- bounds + sums-init (merged) + FC ----------------

__global__ __launch_bounds__(512)
void k_bounds_init(const int* __restrict__ batch, int* __restrict__ bounds,
                   float* __restrict__ sums) {
    int t = threadIdx.x;
    if (t <= N_GRAPHS) {
        int lo = 0, hi = N_NODES;
        while (lo < hi) {
            int mid = (lo + hi) >> 1;
            if (batch[mid] < t) lo = mid + 1; else hi = mid;
        }
        bounds[t] = lo;
    }
    for (int i = t; i < N_GRAPHS * HID_DIM; i += 512) sums[i] = 0.f;
}

__global__ void k_final(const float* __restrict__ sums, const int* __restrict__ bounds,
                        const float* __restrict__ Wfc, const float* __restrict__ bfc,
                        float* __restrict__ out) {
    __shared__ float red[HID_DIM];
    int g = blockIdx.x;
    int c = threadIdx.x;
    float cnt = (float)(bounds[g + 1] - bounds[g]);
    float v = sums[g * HID_DIM + c] / fmaxf(cnt, 1.0f) * Wfc[c];
    red[c] = v;
    __syncthreads();
    for (int s = HID_DIM / 2; s > 0; s >>= 1) {
        if (c < s) red[c] += red[c + s];
        __syncthreads();
    }
    if (c == 0) out[g] = red[0] + bfc[0];
}

// ---------------- launch ----------------

extern "C" void kernel_launch(void* const* d_in, const int* in_sizes, int n_in,
                              void* d_out, int out_size, void* d_ws, size_t ws_size,
                              hipStream_t stream) {
    const float* x    = (const float*)d_in[0];
    const int*   ei   = (const int*)d_in[1];
    const int*   batch= (const int*)d_in[2];
    const float* W1   = (const float*)d_in[3];
    const float* b1   = (const float*)d_in[4];
    const float* W2   = (const float*)d_in[5];
    const float* b2   = (const float*)d_in[6];
    const float* Wfc  = (const float*)d_in[7];
    const float* bfc  = (const float*)d_in[8];
    float* out = (float*)d_out;

    const int* src = ei;
    const int* dst = ei + N_EDGES;

    char* ws = (char*)d_ws;
    const size_t BUF_BYTES = (size_t)N_NODES * HID_DIM * sizeof(float);  // 51.2 MB
    size_t off = 0;
    float* region0   = (float*)(ws + off); off += BUF_BYTES;   // h1
    char*  region1   = (char*) (ws + off); off += BUF_BYTES;   // z/y2b front, xb back
    int*   deg_i     = (int*)  (ws + off); off += 200704;
    int*   cursor    = (int*)  (ws + off); off += 200704;
    float* dinv      = (float*)(ws + off); off += 200704;
    int*   row_start = (int*)  (ws + off); off += 200704;
    int*   col       = (int*)  (ws + off); off += (size_t)N_EDGES * 4;
    unsigned short* Bh1 = (unsigned short*)(ws + off); off += 65536;
    unsigned short* Bl1 = (unsigned short*)(ws + off); off += 65536;
    unsigned short* Bh2 = (unsigned short*)(ws + off); off += 131072;
    unsigned short* Bl2 = (unsigned short*)(ws + off); off += 131072;
    float* sums      = (float*)(ws + off); off += 65536;
    int*   bounds    = (int*)  (ws + off); off += 512;
    int*   blk_tot   = (int*)  (ws + off); off += 512;
    (void)ws_size; (void)in_sizes; (void)n_in; (void)out_size;

    // region1 overlays (lifetimes disjoint):
    //   z   [N,128] fp32 : front — written by agg_x, read by GEMM1, then dead
    //   y2b [N,256] bf16 : front — written by GEMM2, read by agg_pool
    //   xb  [N,128] bf16 : back  — written by x2bf, read by agg_x, then dead
    float*          z   = (float*)region1;
    unsigned short* y2b = (unsigned short*)region1;
    unsigned short* xb  = (unsigned short*)(region1 + (size_t)N_NODES * IN_DIM * sizeof(float));
    float* h1 = region0;

    // 1. CSR build + dinv + weight split + x->bf16
    hipMemsetAsync(deg_i, 0, 2 * 200704, stream);
    k_deg_count<<<(N_EDGES + 255) / 256, 256, 0, stream>>>(dst, deg_i);
    k_scan_blk<<<SCAN_NBLK, SCAN_BLK, 0, stream>>>(deg_i, row_start, dinv, blk_tot);
    k_scan_add<<<SCAN_NBLK, SCAN_BLK, 0, stream>>>(row_start, blk_tot);
    k_csr_fill<<<(N_EDGES + 255) / 256, 256, 0, stream>>>(src, dst, row_start, cursor, col);
    k_x2bf<<<(N_NODES * IN_DIM / 4 + 255) / 256, 256, 0, stream>>>(x, xb);
    k_wsplit<<<(IN_DIM * 256 + 255) / 256, 256, 0, stream>>>(W1, Bh1, Bl1, IN_DIM);
    k_wsplit<<<(HID_DIM * 256 + 255) / 256, 256, 0, stream>>>(W2, Bh2, Bl2, HID_DIM);
    k_bounds_init<<<1, 512, 0, stream>>>(batch, bounds, sums);

    const int gemm_grid = (N_NODES + 63) / 64;  // 782

    // 2. layer 1: z = A_hat @ x ; h1 = relu(z @ W1 + b1)
    k_agg_x<<<(N_NODES + 3) / 4, 256, 0, stream>>>(x, xb, row_start, col, dinv, z);
    k_gemm_mfma<1><<<gemm_grid, 256, 0, stream>>>(z, Bh1, Bl1, dinv, b1, h1, nullptr, N_NODES, IN_DIM);

    // 3. layer 2: y2b = bf16((h1 @ W2) * dinv) ; fused agg+relu+pool
    k_gemm_mfma<0><<<gemm_grid, 256, 0, stream>>>(h1, Bh2, Bl2, dinv, b2, nullptr, y2b, N_NODES, HID_DIM);
    k_agg_pool<<<(N_NODES + 7) / 8, 512, 0, stream>>>(y2b, row_start, col, dinv, b2, batch, sums);

    // 4. fc
    k_final<<<N_GRAPHS, HID_DIM, 0, stream>>>(sums, bounds, Wfc, bfc, out);
}